// Round 7
// baseline (363.145 us; speedup 1.0000x reference)
//
#include <hip/hip_runtime.h>

#define BINS 10

typedef float f32x4 __attribute__((ext_vector_type(4)));

// bin id: reference floor(g * (10 - 1e-4)); identical fp32 ops -> bit-match
__device__ __forceinline__ int bin_of(float xx, float tt) {
    float g = fabsf(xx - tt);
    int b = (int)(g * 9.9999f);
    return b > (BINS - 1) ? (BINS - 1) : b;
}

__device__ __forceinline__ float loss_of(float xx, float tt) {
    return -(tt * __logf(xx) + (1.0f - tt) * __logf(1.0f - xx));
}

// Inline-asm 16B load: cannot be sunk, reordered, or shrunk by the compiler.
// NOTE: the compiler does NOT track vmcnt for asm loads -- caller MUST wait
// via asm s_waitcnt before reading the result, and fence with
// sched_barrier(0) so reg-only consumers can't be hoisted past the wait
// (guide rule #18).
__device__ __forceinline__ f32x4 ld16(const float4* p) {
    f32x4 r;
    asm volatile("global_load_dwordx4 %0, %1, off" : "=v"(r) : "v"(p));
    return r;
}

// Flat-path accumulate: sums via 3-VALU/bin cndmask ladder; counts via a
// single packed u64 (10 bins x 5-bit fields; per-lane count <= 16 fits).
__device__ __forceinline__ void accum_flat(float xx, float tt,
                                           float* __restrict__ sum,
                                           unsigned long long& cpack) {
    int b = bin_of(xx, tt);
    float loss = loss_of(xx, tt);
    cpack += 1ull << (5 * b);
#pragma unroll
    for (int k = 0; k < BINS; ++k)
        sum[k] += (b == k) ? loss : 0.0f;
}

// ---------------------------------------------------------------------------
// Flat kernel, R7: the 8 loads are inline-asm volatile -> guaranteed 8 KB/wave
// in flight (R5/R6 proved source-level hoisting is always undone: VGPR=28,
// ~2 loads in flight, 50% memory duty cycle == the 2.6 TB/s aggregate wall).
// One s_waitcnt vmcnt(0) + sched_barrier(0), then the compute phase; cross-
// wave overlap (waves computing while others' 8 loads are out) provides the
// pipelining.
// ---------------------------------------------------------------------------
__global__ __launch_bounds__(256) void ghm_flat(
    const float4* __restrict__ x4, const float4* __restrict__ t4,
    float* __restrict__ psum, unsigned* __restrict__ pcnt, int nb)
{
    int base = blockIdx.x * 1024 + threadIdx.x;  // float4 index, j-stride 256
    const float4* px = x4 + base;
    const float4* pt = t4 + base;

    // 8 independent coalesced 16 B loads, issued back-to-back (asm volatile:
    // issue order is program order, none can be sunk into the compute).
    f32x4 xa = ld16(px);
    f32x4 ta = ld16(pt);
    f32x4 xb = ld16(px + 256);
    f32x4 tb = ld16(pt + 256);
    f32x4 xc = ld16(px + 512);
    f32x4 tc = ld16(pt + 512);
    f32x4 xd = ld16(px + 768);
    f32x4 td = ld16(pt + 768);

    // Wait for all 8, then fence so no consumer is scheduled above the wait.
    asm volatile("s_waitcnt vmcnt(0)" ::: "memory");
    __builtin_amdgcn_sched_barrier(0);

    float sum[BINS];
#pragma unroll
    for (int k = 0; k < BINS; ++k) sum[k] = 0.0f;
    unsigned long long cpack = 0ull;

    accum_flat(xa[0], ta[0], sum, cpack);
    accum_flat(xa[1], ta[1], sum, cpack);
    accum_flat(xa[2], ta[2], sum, cpack);
    accum_flat(xa[3], ta[3], sum, cpack);
    accum_flat(xb[0], tb[0], sum, cpack);
    accum_flat(xb[1], tb[1], sum, cpack);
    accum_flat(xb[2], tb[2], sum, cpack);
    accum_flat(xb[3], tb[3], sum, cpack);
    accum_flat(xc[0], tc[0], sum, cpack);
    accum_flat(xc[1], tc[1], sum, cpack);
    accum_flat(xc[2], tc[2], sum, cpack);
    accum_flat(xc[3], tc[3], sum, cpack);
    accum_flat(xd[0], td[0], sum, cpack);
    accum_flat(xd[1], td[1], sum, cpack);
    accum_flat(xd[2], td[2], sum, cpack);
    accum_flat(xd[3], td[3], sum, cpack);

    // unpack counts (<= 16 per bin per lane)
    unsigned cnt[BINS];
#pragma unroll
    for (int k = 0; k < BINS; ++k)
        cnt[k] = (unsigned)((cpack >> (5 * k)) & 31ull);

    // wave(64) shuffle reduction
#pragma unroll
    for (int k = 0; k < BINS; ++k) {
#pragma unroll
        for (int off = 32; off > 0; off >>= 1) {
            sum[k] += __shfl_down(sum[k], off, 64);
            cnt[k] += (unsigned)__shfl_down((int)cnt[k], off, 64);
        }
    }

    __shared__ float s_sum[4][BINS];
    __shared__ unsigned s_cnt[4][BINS];
    int lane = threadIdx.x & 63;
    int wv = threadIdx.x >> 6;
    if (lane == 0) {
#pragma unroll
        for (int k = 0; k < BINS; ++k) { s_sum[wv][k] = sum[k]; s_cnt[wv][k] = cnt[k]; }
    }
    __syncthreads();
    if (threadIdx.x < BINS) {
        float s = 0.0f;
        unsigned c = 0u;
#pragma unroll
        for (int w = 0; w < 4; ++w) { s += s_sum[w][threadIdx.x]; c += s_cnt[w][threadIdx.x]; }
        // bin-major layout: finalizer reads coalesced runs per bin
        psum[(size_t)threadIdx.x * nb + blockIdx.x] = s;
        pcnt[(size_t)threadIdx.x * nb + blockIdx.x] = c;
    }
}

// Finalize for the bin-major flat path: per-bin coalesced block reduction.
__global__ __launch_bounds__(256) void ghm_final_bm(
    const float* __restrict__ psum, const unsigned* __restrict__ pcnt,
    float* __restrict__ out, int nb, float Nf)
{
    __shared__ float s_s[4];
    __shared__ unsigned s_c[4];
    __shared__ float tot_s[BINS];
    __shared__ unsigned tot_c[BINS];
    int lane = threadIdx.x & 63;
    int wv = threadIdx.x >> 6;

    for (int k = 0; k < BINS; ++k) {
        float s = 0.0f;
        unsigned c = 0u;
        for (int i = threadIdx.x; i < nb; i += 256) {
            s += psum[(size_t)k * nb + i];
            c += pcnt[(size_t)k * nb + i];
        }
#pragma unroll
        for (int off = 32; off > 0; off >>= 1) {
            s += __shfl_down(s, off, 64);
            c += (unsigned)__shfl_down((int)c, off, 64);
        }
        if (lane == 0) { s_s[wv] = s; s_c[wv] = c; }
        __syncthreads();
        if (threadIdx.x == 0) {
            tot_s[k] = s_s[0] + s_s[1] + s_s[2] + s_s[3];
            tot_c[k] = s_c[0] + s_c[1] + s_c[2] + s_c[3];
        }
        __syncthreads();
    }

    if (threadIdx.x == 0) {
        float nonempty = 0.0f;
#pragma unroll
        for (int k = 0; k < BINS; ++k) nonempty += (tot_c[k] > 0u) ? 1.0f : 0.0f;
        float total = 0.0f;
#pragma unroll
        for (int k = 0; k < BINS; ++k) {
            float gd = (float)tot_c[k] * nonempty;
            gd = gd < 1.0f ? 1.0f : gd;      // clip(gd, 1, None)
            float beta = Nf / gd;
            total += tot_s[k] * beta;
        }
        out[0] = total / Nf;   // mean
    }
}

// ---------------------------------------------------------------------------
// Generic fallback (any N, tiny workspace): R1 structure, verified absmax 0.0.
// ---------------------------------------------------------------------------
__device__ __forceinline__ void accum_gen(float xx, float tt,
                                          float* __restrict__ sum,
                                          unsigned* __restrict__ cnt) {
    int b = bin_of(xx, tt);
    float loss = loss_of(xx, tt);
#pragma unroll
    for (int k = 0; k < BINS; ++k) {
        bool m = (b == k);
        sum[k] += m ? loss : 0.0f;
        cnt[k] += m ? 1u : 0u;
    }
}

template <bool ATOMIC>
__global__ __launch_bounds__(256) void ghm_partial(
    const float* __restrict__ x, const float* __restrict__ t,
    float* __restrict__ psum, unsigned* __restrict__ pcnt,
    int n4, long long n_total)
{
    float sum[BINS];
    unsigned cnt[BINS];
#pragma unroll
    for (int k = 0; k < BINS; ++k) { sum[k] = 0.0f; cnt[k] = 0u; }

    const float4* __restrict__ x4 = (const float4*)x;
    const float4* __restrict__ t4 = (const float4*)t;
    int tid = blockIdx.x * blockDim.x + threadIdx.x;
    int stride = gridDim.x * blockDim.x;

    for (int i = tid; i < n4; i += stride) {
        float4 xv = x4[i];
        float4 tv = t4[i];
        accum_gen(xv.x, tv.x, sum, cnt);
        accum_gen(xv.y, tv.y, sum, cnt);
        accum_gen(xv.z, tv.z, sum, cnt);
        accum_gen(xv.w, tv.w, sum, cnt);
    }
    long long tail_base = (long long)n4 * 4;
    long long rem = n_total - tail_base;
    if ((long long)tid < rem) {
        accum_gen(x[tail_base + tid], t[tail_base + tid], sum, cnt);
    }

#pragma unroll
    for (int k = 0; k < BINS; ++k) {
#pragma unroll
        for (int off = 32; off > 0; off >>= 1) {
            sum[k] += __shfl_down(sum[k], off, 64);
            cnt[k] += (unsigned)__shfl_down((int)cnt[k], off, 64);
        }
    }

    __shared__ float s_sum[4][BINS];
    __shared__ unsigned s_cnt[4][BINS];
    int lane = threadIdx.x & 63;
    int wv = threadIdx.x >> 6;
    if (lane == 0) {
#pragma unroll
        for (int k = 0; k < BINS; ++k) { s_sum[wv][k] = sum[k]; s_cnt[wv][k] = cnt[k]; }
    }
    __syncthreads();
    if (threadIdx.x < BINS) {
        float s = 0.0f;
        unsigned c = 0u;
#pragma unroll
        for (int w = 0; w < 4; ++w) { s += s_sum[w][threadIdx.x]; c += s_cnt[w][threadIdx.x]; }
        if (ATOMIC) {
            atomicAdd(&psum[threadIdx.x], s);
            atomicAdd(&pcnt[threadIdx.x], c);
        } else {
            psum[(size_t)blockIdx.x * BINS + threadIdx.x] = s;
            pcnt[(size_t)blockIdx.x * BINS + threadIdx.x] = c;
        }
    }
}

__global__ void ghm_zero(float* psum, unsigned* pcnt) {
    if (threadIdx.x < BINS) { psum[threadIdx.x] = 0.0f; pcnt[threadIdx.x] = 0u; }
}

// Row-major finalize for the generic path.
__global__ __launch_bounds__(256) void ghm_final(
    const float* __restrict__ psum, const unsigned* __restrict__ pcnt,
    float* __restrict__ out, int nblocks, float Nf)
{
    float sum[BINS];
    unsigned cnt[BINS];
#pragma unroll
    for (int k = 0; k < BINS; ++k) { sum[k] = 0.0f; cnt[k] = 0u; }

    for (int i = threadIdx.x; i < nblocks; i += blockDim.x) {
#pragma unroll
        for (int k = 0; k < BINS; ++k) {
            sum[k] += psum[(size_t)i * BINS + k];
            cnt[k] += pcnt[(size_t)i * BINS + k];
        }
    }

#pragma unroll
    for (int k = 0; k < BINS; ++k) {
#pragma unroll
        for (int off = 32; off > 0; off >>= 1) {
            sum[k] += __shfl_down(sum[k], off, 64);
            cnt[k] += (unsigned)__shfl_down((int)cnt[k], off, 64);
        }
    }

    __shared__ float s_sum[4][BINS];
    __shared__ unsigned s_cnt[4][BINS];
    int lane = threadIdx.x & 63;
    int wv = threadIdx.x >> 6;
    if (lane == 0) {
#pragma unroll
        for (int k = 0; k < BINS; ++k) { s_sum[wv][k] = sum[k]; s_cnt[wv][k] = cnt[k]; }
    }
    __syncthreads();

    if (threadIdx.x == 0) {
        float tot_s[BINS];
        unsigned tot_c[BINS];
#pragma unroll
        for (int k = 0; k < BINS; ++k) {
            float s = 0.0f;
            unsigned c = 0u;
#pragma unroll
            for (int w = 0; w < 4; ++w) { s += s_sum[w][k]; c += s_cnt[w][k]; }
            tot_s[k] = s;
            tot_c[k] = c;
        }
        float nonempty = 0.0f;
#pragma unroll
        for (int k = 0; k < BINS; ++k) nonempty += (tot_c[k] > 0u) ? 1.0f : 0.0f;
        float total = 0.0f;
#pragma unroll
        for (int k = 0; k < BINS; ++k) {
            float gd = (float)tot_c[k] * nonempty;
            gd = gd < 1.0f ? 1.0f : gd;      // clip(gd, 1, None)
            float beta = Nf / gd;
            total += tot_s[k] * beta;
        }
        out[0] = total / Nf;   // mean
    }
}

extern "C" void kernel_launch(void* const* d_in, const int* in_sizes, int n_in,
                              void* d_out, int out_size, void* d_ws, size_t ws_size,
                              hipStream_t stream) {
    const float* x = (const float*)d_in[0];
    const float* t = (const float*)d_in[1];
    float* out = (float*)d_out;

    long long N = (long long)in_sizes[0];
    int n4 = (int)(N / 4);
    float Nf = (float)N;

    // Flat path: exact tiling, 16 elements per lane, no loops.
    if (N % 4096 == 0 && N / 4096 <= 0x7fffffffLL) {
        int nb = (int)(N / 4096);
        size_t need = (size_t)nb * BINS * (sizeof(float) + sizeof(unsigned));
        if (ws_size >= need) {
            float* psum = (float*)d_ws;
            unsigned* pcnt = (unsigned*)(psum + (size_t)BINS * nb);
            ghm_flat<<<nb, 256, 0, stream>>>((const float4*)x, (const float4*)t,
                                             psum, pcnt, nb);
            ghm_final_bm<<<1, 256, 0, stream>>>(psum, pcnt, out, nb, Nf);
            return;
        }
    }

    // Generic fallback.
    const int nblocks = 2048;
    const size_t per_block = (size_t)BINS * (sizeof(float) + sizeof(unsigned)); // 80 B
    if (ws_size >= (size_t)nblocks * per_block) {
        float* psum = (float*)d_ws;
        unsigned* pcnt = (unsigned*)(psum + (size_t)nblocks * BINS);
        ghm_partial<false><<<nblocks, 256, 0, stream>>>(x, t, psum, pcnt, n4, N);
        ghm_final<<<1, 256, 0, stream>>>(psum, pcnt, out, nblocks, Nf);
    } else {
        float* psum = (float*)d_ws;
        unsigned* pcnt = (unsigned*)(psum + BINS);
        ghm_zero<<<1, 64, 0, stream>>>(psum, pcnt);
        ghm_partial<true><<<nblocks, 256, 0, stream>>>(x, t, psum, pcnt, n4, N);
        ghm_final<<<1, 256, 0, stream>>>(psum, pcnt, out, 1, Nf);
    }
}